// Round 15
// baseline (274.886 us; speedup 1.0000x reference)
//
#include <hip/hip_runtime.h>

#define N_NODES 50000
#define N_EDGES 800000
#define F 96
#define NG 100
#define NC 8
#define LSTRIDE 200    // LDS A-tile row stride in ushorts (400B)
#define DMAX 64        // CSR row capacity per node (Poisson(16): P(deg>64) ~ 1e-20)
#define LBK 16         // nodes per layer block
#define NLB 3125       // 50000/16 exactly -> no tail block
#define RPAD 96        // PACKED row length in ushorts (192B = 12*16B)
#define NPB 4688       // prep blocks; 4688 = 8*586
#define ESTR (586 * 256)  // edge-scan stride per residue group

typedef __attribute__((ext_vector_type(8))) short bf16x8;
typedef __attribute__((ext_vector_type(4))) float f32x4;

__device__ inline unsigned short f2b(float f) {  // fp32 -> bf16 RNE
    unsigned int u = __float_as_uint(f);
    u += 0x7fffu + ((u >> 16) & 1u);
    return (unsigned short)(u >> 16);
}

__device__ inline void addu4(float* acc, uint4 u) {
    unsigned int uu[4] = {u.x, u.y, u.z, u.w};
#pragma unroll
    for (int q = 0; q < 4; q++) {
        acc[2 * q]     += __uint_as_float(uu[q] << 16);
        acc[2 * q + 1] += __uint_as_float(uu[q] & 0xffff0000u);
    }
}

// ---------- fused prep: x->bf16 packed rows + W pack + XCD-local CSR + graph bounds ----------
__global__ __launch_bounds__(256) void k_prepfill(
    const float* __restrict__ x, const int* __restrict__ ei,
    const int* __restrict__ batch,
    const float* __restrict__ Wn1, const float* __restrict__ Ws1,
    const float* __restrict__ Wn2, const float* __restrict__ Ws2,
    const float* __restrict__ Wn3, const float* __restrict__ Ws3,
    unsigned short* __restrict__ xb_t, unsigned short* __restrict__ WbT,
    int* __restrict__ ndesc, unsigned short* __restrict__ csr_g,
    int* __restrict__ gbnd) {
    int t = threadIdx.x;
    int b = blockIdx.x;
    int i = b * 256 + t;
    if (i < N_NODES * 24) {  // packed rows: dense write at i*4 ushorts, fully coalesced
        float4 v = *(const float4*)(x + (size_t)i * 4);
        ushort4 p;
        p.x = f2b(v.x); p.y = f2b(v.y); p.z = f2b(v.z); p.w = f2b(v.w);
        *(ushort4*)(xb_t + (size_t)i * 4) = p;
    }
    if (i < 3 * 192 * 96) {
        int l = i / (192 * 96), r = i % (192 * 96);
        int n = r / 192, k = r % 192;
        const float* Wn = (l == 0) ? Wn1 : (l == 1) ? Wn2 : Wn3;
        const float* Ws = (l == 0) ? Ws1 : (l == 1) ? Ws2 : Ws3;
        float v = (k < 96) ? Wn[k * 96 + n] : Ws[(k - 96) * 96 + n];
        WbT[i] = f2b(v);
    }
    if (i <= NG) {  // graph bounds: gbnd[g] = first node with batch >= g (hidden under bulk work)
        int lo = 0, hi = N_NODES;
        while (lo < hi) {
            int mid = (lo + hi) >> 1;
            if (batch[mid] < i) lo = mid + 1; else hi = mid;
        }
        gbnd[i] = lo;
    }
    // edges: residue group p = b&7 handles dst&7 == p only (XCD-local csr lines)
    int p = b & 7;
    int gt = (b >> 3) * 256 + t;
    for (int e = gt; e < N_EDGES; e += ESTR) {
        int dst = ei[N_EDGES + e];
        if ((dst & 7) == p) {
            int src = ei[e];
            int pos = atomicAdd(&ndesc[dst], 1);
            if (pos < DMAX)
                csr_g[((size_t)dst << 6) + pos] = (unsigned short)src;
        }
    }
}

// ---------- fused layer + layer-3 finisher head (fence-free, precomputed bounds) ----------
// r13 lesson: the fence-free finisher protocol is correct; its 42us cost was
// 8 serial cold binary searches per thread. With gbnd precomputed in prep the
// finisher is ~3us of pipelined loads.
__global__ __launch_bounds__(256, 4) void k_layer(
    const unsigned short* __restrict__ hin,
    const unsigned short* __restrict__ csr_g,
    const int* __restrict__ ndesc,
    const unsigned short* __restrict__ WbT,  // [96][192] bf16 (n-major)
    const float* __restrict__ bias,
    unsigned short* __restrict__ hout, int relu, int out_bf16,
    const int* __restrict__ batch, float* __restrict__ pools,
    const int* __restrict__ gbnd, const float* __restrict__ Wl,
    const float* __restrict__ bl, float* __restrict__ out,
    int* __restrict__ done) {
    __shared__ unsigned short A[LBK * LSTRIDE];  // 6.4 KB
    __shared__ float pl[2 * F];                  // layer-3 pooling accum
    __shared__ int fin;
    int t = threadIdx.x;
    int row0 = blockIdx.x * LBK;
    int nl = t >> 4;
    int h = (t >> 2) & 3;
    int q = t & 3;
    int node = row0 + nl;                 // always < N_NODES (50000 = 3125*16)
    int deg = ndesc[node];
    if (deg > DMAX) deg = DMAX;
    size_t ebase = (size_t)node << 6;

    if (!out_bf16 && t < 2 * F) pl[t] = 0.f;

    // --- self row -> LDS (h==0 lanes cover all 192B) ---
    if (h == 0) {
        const uint4* sp = (const uint4*)(hin + (size_t)node * RPAD + (q << 3));
        uint4 s0 = sp[0], s1 = sp[4], s2 = sp[8];
        *(uint4*)&A[nl * LSTRIDE + 96 + 0 * 32 + q * 8] = s0;
        *(uint4*)&A[nl * LSTRIDE + 96 + 1 * 32 + q * 8] = s1;
        *(uint4*)&A[nl * LSTRIDE + 96 + 2 * 32 + q * 8] = s2;
    }

    // --- gather: quarter h handles edges e ≡ h (mod 4), 2 edges/iter ---
    float ac[24];
#pragma unroll
    for (int k = 0; k < 24; k++) ac[k] = 0.f;
    {
        int e = h;
        for (; e + 4 < deg; e += 8) {
            int s0 = csr_g[ebase + e];
            int s1 = csr_g[ebase + e + 4];
            const uint4* p0 = (const uint4*)(hin + (size_t)s0 * RPAD + (q << 3));
            const uint4* p1 = (const uint4*)(hin + (size_t)s1 * RPAD + (q << 3));
            uint4 a0 = p0[0], a1 = p0[4], a2 = p0[8];
            uint4 b0 = p1[0], b1 = p1[4], b2 = p1[8];
            addu4(ac + 0, a0); addu4(ac + 8, a1); addu4(ac + 16, a2);
            addu4(ac + 0, b0); addu4(ac + 8, b1); addu4(ac + 16, b2);
        }
        if (e < deg) {
            int s0 = csr_g[ebase + e];
            const uint4* p0 = (const uint4*)(hin + (size_t)s0 * RPAD + (q << 3));
            uint4 a0 = p0[0], a1 = p0[4], a2 = p0[8];
            addu4(ac + 0, a0); addu4(ac + 8, a1); addu4(ac + 16, a2);
        }
    }

    // --- combine quarters in-wave: lane bits [3:2] = h ---
#pragma unroll
    for (int k = 0; k < 24; k++) {
        ac[k] += __shfl_xor(ac[k], 4, 64);
        ac[k] += __shfl_xor(ac[k], 8, 64);
    }

    // --- pack aggregated features to LDS (h==0 lanes) ---
    if (h == 0) {
#pragma unroll
        for (int j = 0; j < 3; j++) {
            uint4 pk;
            pk.x = ((unsigned int)f2b(ac[j * 8 + 1]) << 16) | f2b(ac[j * 8 + 0]);
            pk.y = ((unsigned int)f2b(ac[j * 8 + 3]) << 16) | f2b(ac[j * 8 + 2]);
            pk.z = ((unsigned int)f2b(ac[j * 8 + 5]) << 16) | f2b(ac[j * 8 + 4]);
            pk.w = ((unsigned int)f2b(ac[j * 8 + 7]) << 16) | f2b(ac[j * 8 + 6]);
            *(uint4*)&A[nl * LSTRIDE + j * 32 + q * 8] = pk;
        }
    }
    __syncthreads();

    // --- MFMA: wave w computes nt in {w, w+4} (waves 0,1: 2 tiles; 2,3: 1) ---
    int wave = t >> 6;
    int lane = t & 63;
    int m = lane & 15;
    int ko = (lane >> 4) * 8;
    f32x4 acc[2];
    acc[0] = (f32x4){0.f, 0.f, 0.f, 0.f};
    acc[1] = (f32x4){0.f, 0.f, 0.f, 0.f};
    int ntc = (wave < 2) ? 2 : 1;
#pragma unroll
    for (int j = 0; j < 3; j++) {
        bf16x8 a0 = *(bf16x8*)&A[m * LSTRIDE + j * 32 + ko];
        bf16x8 a1 = *(bf16x8*)&A[m * LSTRIDE + 96 + j * 32 + ko];
        for (int ii = 0; ii < ntc; ii++) {
            int nt = wave + ii * 4;
            bf16x8 b0 = *(const bf16x8*)(WbT + (size_t)(nt * 16 + m) * 192 + j * 32 + ko);
            acc[ii] = __builtin_amdgcn_mfma_f32_16x16x32_bf16(a0, b0, acc[ii], 0, 0, 0);
            bf16x8 b1 = *(const bf16x8*)(WbT + (size_t)(nt * 16 + m) * 192 + 96 + j * 32 + ko);
            acc[ii] = __builtin_amdgcn_mfma_f32_16x16x32_bf16(a1, b1, acc[ii], 0, 0, 0);
        }
    }

    if (out_bf16) {
        for (int ii = 0; ii < ntc; ii++) {
            int col = (wave + ii * 4) * 16 + m;
            float bv = bias[col];
#pragma unroll
            for (int r = 0; r < 4; r++) {
                int rl = ((lane >> 4) << 2) + r;
                int onode = row0 + rl;
                float v = acc[ii][r] + bv;
                if (relu) v = fmaxf(v, 0.f);
                hout[(size_t)onode * RPAD + col] = f2b(v);
            }
        }
    } else {
        // layer 3: fused mean-pool accumulation (block spans <=2 graphs normally)
        int gA = batch[row0];
        for (int ii = 0; ii < ntc; ii++) {
            int col = (wave + ii * 4) * 16 + m;
            float bv = bias[col];
            float s0 = 0.f, s1 = 0.f;
#pragma unroll
            for (int r = 0; r < 4; r++) {
                int rl = ((lane >> 4) << 2) + r;
                int onode = row0 + rl;
                float v = acc[ii][r] + bv;
                int slot = batch[onode] - gA;
                if (slot == 0) s0 += v;
                else if (slot == 1) s1 += v;
                else atomicAdd(&pools[(size_t)(gA + slot) * F + col], v);  // freak case
            }
            if (s0 != 0.f) atomicAdd(&pl[col], s0);
            if (s1 != 0.f) atomicAdd(&pl[F + col], s1);
        }
        __syncthreads();
        if (t < 2 * F) {
            int gl = t / F;
            float v = pl[t];
            if (v != 0.f && gA + gl < NG)
                atomicAdd(&pools[(size_t)(gA + gl) * F + (t % F)], v);
        }
        // --- fence-free finisher (protocol validated r13): pool updates are
        // device-scope atomics; __syncthreads drains vmcnt; relaxed done ok. ---
        __syncthreads();
        if (t == 0) {
            fin = (__hip_atomic_fetch_add(done, 1, __ATOMIC_RELAXED,
                                          __HIP_MEMORY_SCOPE_AGENT) == NLB - 1) ? 1 : 0;
        }
        __syncthreads();
        if (fin) {
            for (int idx = t; idx < NG * NC; idx += 256) {
                int g = idx >> 3, c = idx & 7;
                int beg = gbnd[g], end = gbnd[g + 1];
                float inv = 1.f / fmaxf((float)(end - beg), 1.f);
                float s = 0.f;
#pragma unroll 8
                for (int k = 0; k < F; k++) {
                    float pv = __hip_atomic_load(&pools[(size_t)g * F + k],
                                                 __ATOMIC_RELAXED, __HIP_MEMORY_SCOPE_AGENT);
                    s += pv * Wl[k * NC + c];
                }
                out[idx] = s * inv + bl[c];
            }
        }
    }
}

extern "C" void kernel_launch(void* const* d_in, const int* in_sizes, int n_in,
                              void* d_out, int out_size, void* d_ws, size_t ws_size,
                              hipStream_t stream) {
    const float* x   = (const float*)d_in[0];
    const int* ei    = (const int*)d_in[1];
    const int* batch = (const int*)d_in[3];
    const float* Wn1 = (const float*)d_in[4];
    const float* Ws1 = (const float*)d_in[5];
    const float* b1  = (const float*)d_in[6];
    const float* Wn2 = (const float*)d_in[7];
    const float* Ws2 = (const float*)d_in[8];
    const float* b2  = (const float*)d_in[9];
    const float* Wn3 = (const float*)d_in[10];
    const float* Ws3 = (const float*)d_in[11];
    const float* b3  = (const float*)d_in[12];
    const float* Wl  = (const float*)d_in[13];
    const float* bl  = (const float*)d_in[14];
    float* out = (float*)d_out;

    char* w = (char*)d_ws;
    unsigned short* xb_t  = (unsigned short*)w; w += (size_t)N_NODES * RPAD * 2;
    unsigned short* h1    = (unsigned short*)w; w += (size_t)N_NODES * RPAD * 2;
    unsigned short* h2    = (unsigned short*)w; w += (size_t)N_NODES * RPAD * 2;
    unsigned short* WbT   = (unsigned short*)w; w += (size_t)3 * 192 * 96 * 2;
    w = (char*)(((size_t)w + 255) & ~(size_t)255);
    unsigned short* csr_g = (unsigned short*)w; w += (size_t)N_NODES * DMAX * 2;
    int* ndesc           = (int*)w;             w += (size_t)N_NODES * 4;
    float* pools         = (float*)w;           w += (size_t)NG * F * 4;
    int* done            = (int*)w;             w += 256;        // zeroed with ndesc+pools
    int* gbnd            = (int*)w;             w += (NG + 1) * 4;  // written by prep

    // one memset covers ndesc + pools + done (contiguous)
    hipMemsetAsync(ndesc, 0, (size_t)N_NODES * 4 + (size_t)NG * F * 4 + 256, stream);
    k_prepfill<<<NPB, 256, 0, stream>>>(
        x, ei, batch, Wn1, Ws1, Wn2, Ws2, Wn3, Ws3, xb_t, WbT, ndesc, csr_g, gbnd);

    k_layer<<<NLB, 256, 0, stream>>>(xb_t, csr_g, ndesc, WbT,                b1, h1, 1, 1,
                                     batch, pools, gbnd, Wl, bl, out, done);
    k_layer<<<NLB, 256, 0, stream>>>(h1,   csr_g, ndesc, WbT + 192 * 96,     b2, h2, 1, 1,
                                     batch, pools, gbnd, Wl, bl, out, done);
    k_layer<<<NLB, 256, 0, stream>>>(h2,   csr_g, ndesc, WbT + 2 * 192 * 96, b3, h2, 0, 0,
                                     batch, pools, gbnd, Wl, bl, out, done);
}

// Round 16
// 254.349 us; speedup vs baseline: 1.0807x; 1.0807x over previous
//
#include <hip/hip_runtime.h>

#define N_NODES 50000
#define N_EDGES 800000
#define F 96
#define NG 100
#define NC 8
#define LSTRIDE 200    // LDS A-tile row stride in ushorts (400B)
#define DMAX 64        // CSR row capacity per node (Poisson(16): P(deg>64) ~ 1e-20)
#define LBK 16         // nodes per layer block
#define NLB 3125       // 50000/16 exactly -> no tail block
#define RPAD 96        // PACKED row length in ushorts (192B = 12*16B)
#define NPB 4688       // prep blocks; 4688 = 8*586
#define ESTR (586 * 256)  // edge-scan stride per residue group

typedef __attribute__((ext_vector_type(8))) short bf16x8;
typedef __attribute__((ext_vector_type(4))) float f32x4;

__device__ inline unsigned short f2b(float f) {  // fp32 -> bf16 RNE
    unsigned int u = __float_as_uint(f);
    u += 0x7fffu + ((u >> 16) & 1u);
    return (unsigned short)(u >> 16);
}

__device__ inline void addu4(float* acc, uint4 u) {
    unsigned int uu[4] = {u.x, u.y, u.z, u.w};
#pragma unroll
    for (int q = 0; q < 4; q++) {
        acc[2 * q]     += __uint_as_float(uu[q] << 16);
        acc[2 * q + 1] += __uint_as_float(uu[q] & 0xffff0000u);
    }
}

// ---------- fused prep: x->bf16 packed rows + W pack + XCD-local CSR ----------
// Edge scatter dominated prep (r4 probe: 44MB of repeated partial-line csr
// writebacks). Residue partition dst&7 == blockIdx&7: each node's 128B csr
// line is written by one XCD-group only -> stays L2-resident, one writeback.
// Each edge is handled exactly once (residue match) under any block->XCD map.
__global__ __launch_bounds__(256) void k_prepfill(
    const float* __restrict__ x, const int* __restrict__ ei,
    const float* __restrict__ Wn1, const float* __restrict__ Ws1,
    const float* __restrict__ Wn2, const float* __restrict__ Ws2,
    const float* __restrict__ Wn3, const float* __restrict__ Ws3,
    unsigned short* __restrict__ xb_t, unsigned short* __restrict__ WbT,
    int* __restrict__ ndesc, unsigned short* __restrict__ csr_g) {
    int t = threadIdx.x;
    int b = blockIdx.x;
    int i = b * 256 + t;
    if (i < N_NODES * 24) {  // packed rows: dense write at i*4 ushorts, fully coalesced
        float4 v = *(const float4*)(x + (size_t)i * 4);
        ushort4 p;
        p.x = f2b(v.x); p.y = f2b(v.y); p.z = f2b(v.z); p.w = f2b(v.w);
        *(ushort4*)(xb_t + (size_t)i * 4) = p;
    }
    if (i < 3 * 192 * 96) {
        int l = i / (192 * 96), r = i % (192 * 96);
        int n = r / 192, k = r % 192;
        const float* Wn = (l == 0) ? Wn1 : (l == 1) ? Wn2 : Wn3;
        const float* Ws = (l == 0) ? Ws1 : (l == 1) ? Ws2 : Ws3;
        float v = (k < 96) ? Wn[k * 96 + n] : Ws[(k - 96) * 96 + n];
        WbT[i] = f2b(v);
    }
    // edges: residue group p = b&7 handles dst&7 == p only
    int p = b & 7;
    int gt = (b >> 3) * 256 + t;
    for (int e = gt; e < N_EDGES; e += ESTR) {
        int dst = ei[N_EDGES + e];
        if ((dst & 7) == p) {
            int src = ei[e];
            int pos = atomicAdd(&ndesc[dst], 1);
            if (pos < DMAX)
                csr_g[((size_t)dst << 6) + pos] = (unsigned short)src;
        }
    }
}

// ---------- fused layer: 16 thr/node gather (4-way edge split, shfl combine) + MFMA ----------
// out_bf16==0 (layer 3): pooling fused — per-block LDS f32 accum, then atomics.
// Head stays a separate dispatch: fusion's serial tail (r11/r13/r15) always cost
// more than the saved dispatch+gap.
__global__ __launch_bounds__(256, 4) void k_layer(
    const unsigned short* __restrict__ hin,
    const unsigned short* __restrict__ csr_g,
    const int* __restrict__ ndesc,
    const unsigned short* __restrict__ WbT,  // [96][192] bf16 (n-major)
    const float* __restrict__ bias,
    unsigned short* __restrict__ hout, int relu, int out_bf16,
    const int* __restrict__ batch, float* __restrict__ pools) {
    __shared__ unsigned short A[LBK * LSTRIDE];  // 6.4 KB
    __shared__ float pl[2 * F];                  // layer-3 pooling accum
    int t = threadIdx.x;
    int row0 = blockIdx.x * LBK;
    int nl = t >> 4;
    int h = (t >> 2) & 3;
    int q = t & 3;
    int node = row0 + nl;                 // always < N_NODES (50000 = 3125*16)
    int deg = ndesc[node];
    if (deg > DMAX) deg = DMAX;
    size_t ebase = (size_t)node << 6;

    if (!out_bf16 && t < 2 * F) pl[t] = 0.f;

    // --- self row -> LDS (h==0 lanes cover all 192B) ---
    if (h == 0) {
        const uint4* sp = (const uint4*)(hin + (size_t)node * RPAD + (q << 3));
        uint4 s0 = sp[0], s1 = sp[4], s2 = sp[8];
        *(uint4*)&A[nl * LSTRIDE + 96 + 0 * 32 + q * 8] = s0;
        *(uint4*)&A[nl * LSTRIDE + 96 + 1 * 32 + q * 8] = s1;
        *(uint4*)&A[nl * LSTRIDE + 96 + 2 * 32 + q * 8] = s2;
    }

    // --- gather: quarter h handles edges e ≡ h (mod 4), 2 edges/iter ---
    float ac[24];
#pragma unroll
    for (int k = 0; k < 24; k++) ac[k] = 0.f;
    {
        int e = h;
        for (; e + 4 < deg; e += 8) {
            int s0 = csr_g[ebase + e];
            int s1 = csr_g[ebase + e + 4];
            const uint4* p0 = (const uint4*)(hin + (size_t)s0 * RPAD + (q << 3));
            const uint4* p1 = (const uint4*)(hin + (size_t)s1 * RPAD + (q << 3));
            uint4 a0 = p0[0], a1 = p0[4], a2 = p0[8];
            uint4 b0 = p1[0], b1 = p1[4], b2 = p1[8];
            addu4(ac + 0, a0); addu4(ac + 8, a1); addu4(ac + 16, a2);
            addu4(ac + 0, b0); addu4(ac + 8, b1); addu4(ac + 16, b2);
        }
        if (e < deg) {
            int s0 = csr_g[ebase + e];
            const uint4* p0 = (const uint4*)(hin + (size_t)s0 * RPAD + (q << 3));
            uint4 a0 = p0[0], a1 = p0[4], a2 = p0[8];
            addu4(ac + 0, a0); addu4(ac + 8, a1); addu4(ac + 16, a2);
        }
    }

    // --- combine quarters in-wave: lane bits [3:2] = h ---
#pragma unroll
    for (int k = 0; k < 24; k++) {
        ac[k] += __shfl_xor(ac[k], 4, 64);
        ac[k] += __shfl_xor(ac[k], 8, 64);
    }

    // --- pack aggregated features to LDS (h==0 lanes) ---
    if (h == 0) {
#pragma unroll
        for (int j = 0; j < 3; j++) {
            uint4 pk;
            pk.x = ((unsigned int)f2b(ac[j * 8 + 1]) << 16) | f2b(ac[j * 8 + 0]);
            pk.y = ((unsigned int)f2b(ac[j * 8 + 3]) << 16) | f2b(ac[j * 8 + 2]);
            pk.z = ((unsigned int)f2b(ac[j * 8 + 5]) << 16) | f2b(ac[j * 8 + 4]);
            pk.w = ((unsigned int)f2b(ac[j * 8 + 7]) << 16) | f2b(ac[j * 8 + 6]);
            *(uint4*)&A[nl * LSTRIDE + j * 32 + q * 8] = pk;
        }
    }
    __syncthreads();

    // --- MFMA: wave w computes nt in {w, w+4} (waves 0,1: 2 tiles; 2,3: 1) ---
    int wave = t >> 6;
    int lane = t & 63;
    int m = lane & 15;
    int ko = (lane >> 4) * 8;
    f32x4 acc[2];
    acc[0] = (f32x4){0.f, 0.f, 0.f, 0.f};
    acc[1] = (f32x4){0.f, 0.f, 0.f, 0.f};
    int ntc = (wave < 2) ? 2 : 1;
#pragma unroll
    for (int j = 0; j < 3; j++) {
        bf16x8 a0 = *(bf16x8*)&A[m * LSTRIDE + j * 32 + ko];
        bf16x8 a1 = *(bf16x8*)&A[m * LSTRIDE + 96 + j * 32 + ko];
        for (int ii = 0; ii < ntc; ii++) {
            int nt = wave + ii * 4;
            bf16x8 b0 = *(const bf16x8*)(WbT + (size_t)(nt * 16 + m) * 192 + j * 32 + ko);
            acc[ii] = __builtin_amdgcn_mfma_f32_16x16x32_bf16(a0, b0, acc[ii], 0, 0, 0);
            bf16x8 b1 = *(const bf16x8*)(WbT + (size_t)(nt * 16 + m) * 192 + 96 + j * 32 + ko);
            acc[ii] = __builtin_amdgcn_mfma_f32_16x16x32_bf16(a1, b1, acc[ii], 0, 0, 0);
        }
    }

    if (out_bf16) {
        for (int ii = 0; ii < ntc; ii++) {
            int col = (wave + ii * 4) * 16 + m;
            float bv = bias[col];
#pragma unroll
            for (int r = 0; r < 4; r++) {
                int rl = ((lane >> 4) << 2) + r;
                int onode = row0 + rl;
                float v = acc[ii][r] + bv;
                if (relu) v = fmaxf(v, 0.f);
                hout[(size_t)onode * RPAD + col] = f2b(v);
            }
        }
    } else {
        // layer 3: fused mean-pool accumulation (block spans <=2 graphs normally)
        int gA = batch[row0];
        for (int ii = 0; ii < ntc; ii++) {
            int col = (wave + ii * 4) * 16 + m;
            float bv = bias[col];
            float s0 = 0.f, s1 = 0.f;
#pragma unroll
            for (int r = 0; r < 4; r++) {
                int rl = ((lane >> 4) << 2) + r;
                int onode = row0 + rl;
                float v = acc[ii][r] + bv;
                int slot = batch[onode] - gA;
                if (slot == 0) s0 += v;
                else if (slot == 1) s1 += v;
                else atomicAdd(&pools[(size_t)(gA + slot) * F + col], v);  // freak case
            }
            if (s0 != 0.f) atomicAdd(&pl[col], s0);
            if (s1 != 0.f) atomicAdd(&pl[F + col], s1);
        }
        __syncthreads();
        if (t < 2 * F) {
            int gl = t / F;
            float v = pl[t];
            if (v != 0.f && gA + gl < NG)
                atomicAdd(&pools[(size_t)(gA + gl) * F + (t % F)], v);
        }
    }
}

// ---------- head: divide pooled sums by counts, classify ----------
__global__ __launch_bounds__(128) void k_head(const float* __restrict__ pools,
                                              const int* __restrict__ batch,
                                              const float* __restrict__ Wl,
                                              const float* __restrict__ bl,
                                              float* __restrict__ out) {
    __shared__ float pool[F];
    __shared__ int bounds[2];
    int g = blockIdx.x;
    int t = threadIdx.x;
    if (t < 2) {
        int target = g + t;
        int lo = 0, hi = N_NODES;
        while (lo < hi) {
            int mid = (lo + hi) >> 1;
            if (batch[mid] < target) lo = mid + 1; else hi = mid;
        }
        bounds[t] = lo;
    }
    __syncthreads();
    float inv = 1.f / fmaxf((float)(bounds[1] - bounds[0]), 1.f);
    if (t < F) pool[t] = pools[(size_t)g * F + t] * inv;
    __syncthreads();
    if (t < NC) {
        float s = bl[t];
#pragma unroll 8
        for (int k = 0; k < F; k++) s += pool[k] * Wl[k * NC + t];
        out[g * NC + t] = s;
    }
}

extern "C" void kernel_launch(void* const* d_in, const int* in_sizes, int n_in,
                              void* d_out, int out_size, void* d_ws, size_t ws_size,
                              hipStream_t stream) {
    const float* x   = (const float*)d_in[0];
    const int* ei    = (const int*)d_in[1];
    const int* batch = (const int*)d_in[3];
    const float* Wn1 = (const float*)d_in[4];
    const float* Ws1 = (const float*)d_in[5];
    const float* b1  = (const float*)d_in[6];
    const float* Wn2 = (const float*)d_in[7];
    const float* Ws2 = (const float*)d_in[8];
    const float* b2  = (const float*)d_in[9];
    const float* Wn3 = (const float*)d_in[10];
    const float* Ws3 = (const float*)d_in[11];
    const float* b3  = (const float*)d_in[12];
    const float* Wl  = (const float*)d_in[13];
    const float* bl  = (const float*)d_in[14];
    float* out = (float*)d_out;

    char* w = (char*)d_ws;
    unsigned short* xb_t  = (unsigned short*)w; w += (size_t)N_NODES * RPAD * 2;
    unsigned short* h1    = (unsigned short*)w; w += (size_t)N_NODES * RPAD * 2;
    unsigned short* h2    = (unsigned short*)w; w += (size_t)N_NODES * RPAD * 2;
    unsigned short* WbT   = (unsigned short*)w; w += (size_t)3 * 192 * 96 * 2;
    w = (char*)(((size_t)w + 255) & ~(size_t)255);
    unsigned short* csr_g = (unsigned short*)w; w += (size_t)N_NODES * DMAX * 2;
    int* ndesc           = (int*)w;             w += (size_t)N_NODES * 4;
    float* pools         = (float*)w;           w += (size_t)NG * F * 4;  // adjacent: one memset

    hipMemsetAsync(ndesc, 0, (size_t)N_NODES * 4 + (size_t)NG * F * 4, stream);
    k_prepfill<<<NPB, 256, 0, stream>>>(
        x, ei, Wn1, Ws1, Wn2, Ws2, Wn3, Ws3, xb_t, WbT, ndesc, csr_g);

    k_layer<<<NLB, 256, 0, stream>>>(xb_t, csr_g, ndesc, WbT,                b1, h1, 1, 1, batch, pools);
    k_layer<<<NLB, 256, 0, stream>>>(h1,   csr_g, ndesc, WbT + 192 * 96,     b2, h2, 1, 1, batch, pools);
    k_layer<<<NLB, 256, 0, stream>>>(h2,   csr_g, ndesc, WbT + 2 * 192 * 96, b3, h2, 0, 0, batch, pools);

    k_head<<<NG, 128, 0, stream>>>(pools, batch, Wl, bl, out);
}